// Round 4
// baseline (29.055 us; speedup 1.0000x reference)
//
#include <hip/hip_runtime.h>

#define NP 1048576
#define BLOCK 256
#define PPT 4
#define NBLK (NP / (BLOCK * PPT))   /* 1024 */
#define W_IN 0.001f
#define W_OUT 1.0f
#define TOL 1e-8f
#define SQRT3 1.7320508f

// Fully fused: map (closed-form octahedron geometry) + block reduce +
// last-block-finalize via agent-scope counter. Single dispatch.
__global__ __launch_bounds__(BLOCK) void pbl_fused(
    const float* __restrict__ pts, float* __restrict__ ws, float* __restrict__ out)
{
    __shared__ float s_s[BLOCK/64], s_c[BLOCK/64], s_m[BLOCK/64];
    __shared__ int s_last;

    const int lt = threadIdx.x;
    const int tid = blockIdx.x * BLOCK + lt;
    const float4* p4 = (const float4*)pts;
    float4 f0 = p4[tid*3+0];
    float4 f1 = p4[tid*3+1];
    float4 f2 = p4[tid*3+2];
    float px[PPT] = {f0.x, f0.w, f1.z, f2.y};
    float py[PPT] = {f0.y, f1.x, f1.w, f2.z};
    float pz[PPT] = {f0.z, f1.y, f2.x, f2.w};

    float sum_in = 0.f, cnt_in = 0.f, mx_out = 0.f;
    #pragma unroll
    for (int i = 0; i < PPT; ++i) {
        float ux = fabsf(px[i]), uy = fabsf(py[i]), uz = fabsf(pz[i]);
        float s1 = ux + uy + uz;
        float hi = fmaxf(ux, fmaxf(uy, uz));
        float lo = fminf(ux, fminf(uy, uz));
        float mid = s1 - hi - lo;
        float ss = fmaf(px[i], px[i], fmaf(py[i], py[i], pz[i]*pz[i]));

        // inside test: max plane violation == (s1-1)/sqrt3 for this hull
        bool inside = (s1 - 1.f) <= TOL * SQRT3;

        // min sq dist to vertices {+-e_i}: |p|^2 - 2*max|p_i| + 1
        float d2v = fmaf(-2.f, hi, ss) + 1.f;

        // exact sq dist to octahedron surface: simplex projection (sorted u)
        float t3 = (s1 - 1.f) * (1.f/3.f);
        float t2 = (hi + mid - 1.f) * 0.5f;
        float t1 = hi - 1.f;
        float d2_3 = 3.f * t3 * t3;
        float d2_2 = fmaf(lo, lo, 2.f * t2 * t2);
        float d2_1 = fmaf(t1, t1, fmaf(mid, mid, lo * lo));
        float sq = (lo > t3) ? d2_3 : ((mid > t2) ? d2_2 : d2_1);

        sum_in += inside ? d2v : 0.f;
        cnt_in += inside ? 1.f : 0.f;
        mx_out  = inside ? mx_out : fmaxf(mx_out, sq);
    }

    // wave reduce (64 lanes)
    #pragma unroll
    for (int o = 32; o > 0; o >>= 1) {
        sum_in += __shfl_down(sum_in, o);
        cnt_in += __shfl_down(cnt_in, o);
        mx_out  = fmaxf(mx_out, __shfl_down(mx_out, o));
    }
    const int wave = lt >> 6, lane = lt & 63;
    if (lane == 0) { s_s[wave] = sum_in; s_c[wave] = cnt_in; s_m[wave] = mx_out; }
    __syncthreads();

    if (lt == 0) {
        float S = 0.f, C = 0.f, M = 0.f;
        #pragma unroll
        for (int i = 0; i < BLOCK/64; ++i) { S += s_s[i]; C += s_c[i]; M = fmaxf(M, s_m[i]); }
        // publish partials at agent scope (coherent point), then release-count
        __hip_atomic_store(&ws[blockIdx.x],          S, __ATOMIC_RELAXED, __HIP_MEMORY_SCOPE_AGENT);
        __hip_atomic_store(&ws[NBLK + blockIdx.x],   C, __ATOMIC_RELAXED, __HIP_MEMORY_SCOPE_AGENT);
        __hip_atomic_store(&ws[2*NBLK + blockIdx.x], M, __ATOMIC_RELAXED, __HIP_MEMORY_SCOPE_AGENT);
        unsigned ret = __hip_atomic_fetch_add((unsigned*)(ws + 3*NBLK), 1u,
                                              __ATOMIC_ACQ_REL, __HIP_MEMORY_SCOPE_AGENT);
        // works for ANY initial counter value (poison-safe): exactly one block
        // among each consecutive NBLK increments satisfies this
        s_last = ((ret & (NBLK - 1)) == (NBLK - 1)) ? 1 : 0;
    }
    __syncthreads();

    if (s_last) {
        // final reduction: 256 threads x 4 partials per array, coherent loads
        float S = 0.f, C = 0.f, M = 0.f;
        #pragma unroll
        for (int j = 0; j < 4; ++j) {
            int idx = lt * 4 + j;
            S += __hip_atomic_load(&ws[idx],          __ATOMIC_RELAXED, __HIP_MEMORY_SCOPE_AGENT);
            C += __hip_atomic_load(&ws[NBLK + idx],   __ATOMIC_RELAXED, __HIP_MEMORY_SCOPE_AGENT);
            M  = fmaxf(M, __hip_atomic_load(&ws[2*NBLK + idx], __ATOMIC_RELAXED, __HIP_MEMORY_SCOPE_AGENT));
        }
        #pragma unroll
        for (int o = 32; o > 0; o >>= 1) {
            S += __shfl_down(S, o);
            C += __shfl_down(C, o);
            M  = fmaxf(M, __shfl_down(M, o));
        }
        if (lane == 0) { s_s[wave] = S; s_c[wave] = C; s_m[wave] = M; }
        __syncthreads();
        if (lt == 0) {
            S = s_s[0] + s_s[1] + s_s[2] + s_s[3];
            C = s_c[0] + s_c[1] + s_c[2] + s_c[3];
            M = fmaxf(fmaxf(s_m[0], s_m[1]), fmaxf(s_m[2], s_m[3]));
            float li = (C > 0.f) ? W_IN * S / C : 0.f;
            float nout = (float)NP - C;
            float lo = (nout > 0.f) ? W_OUT * M : 0.f;
            out[0] = li + lo;
        }
    }
}

extern "C" void kernel_launch(void* const* d_in, const int* in_sizes, int n_in,
                              void* d_out, int out_size, void* d_ws, size_t ws_size,
                              hipStream_t stream) {
    const float* pts = (const float*)d_in[0];
    float* ws = (float*)d_ws;
    float* out = (float*)d_out;
    pbl_fused<<<NBLK, BLOCK, 0, stream>>>(pts, ws, out);
}

// Round 5
// 22.895 us; speedup vs baseline: 1.2691x; 1.2691x over previous
//
#include <hip/hip_runtime.h>

#define NP 1048576
#define BLOCK 256
#define PPT 4
#define NBLK (NP / (BLOCK * PPT))   /* 1024 */
#define GROUPS 32
#define GSIZE (NBLK / GROUPS)       /* 32 */
#define W_IN 0.001f
#define W_OUT 1.0f
#define TOL 1e-8f
#define SQRT3 1.7320508f

// ws float layout:
//   [0,1024)      per-block S
//   [1024,2048)   per-block C
//   [2048,3072)   per-block M
//   u32 counters level-1 at 3072 + g*16   (64B apart, g<32)
//   group aggregates: S_g at 3584+g, C_g at 3616+g, M_g at 3648+g
//   u32 counter level-2 at 3712

__global__ __launch_bounds__(BLOCK) void pbl_fused(
    const float* __restrict__ pts, float* __restrict__ ws, float* __restrict__ out)
{
    __shared__ float s_s[BLOCK/64], s_c[BLOCK/64], s_m[BLOCK/64];
    __shared__ int s_last;

    const int lt = threadIdx.x;
    const int tid = blockIdx.x * BLOCK + lt;
    const float4* p4 = (const float4*)pts;
    float4 f0 = p4[tid*3+0];
    float4 f1 = p4[tid*3+1];
    float4 f2 = p4[tid*3+2];
    float px[PPT] = {f0.x, f0.w, f1.z, f2.y};
    float py[PPT] = {f0.y, f1.x, f1.w, f2.z};
    float pz[PPT] = {f0.z, f1.y, f2.x, f2.w};

    float sum_in = 0.f, cnt_in = 0.f, mx_out = 0.f;
    #pragma unroll
    for (int i = 0; i < PPT; ++i) {
        float ux = fabsf(px[i]), uy = fabsf(py[i]), uz = fabsf(pz[i]);
        float s1 = ux + uy + uz;
        float hi = fmaxf(ux, fmaxf(uy, uz));
        float lo = fminf(ux, fminf(uy, uz));
        float mid = s1 - hi - lo;
        float ss = fmaf(px[i], px[i], fmaf(py[i], py[i], pz[i]*pz[i]));

        bool inside = (s1 - 1.f) <= TOL * SQRT3;           // max plane violation
        float d2v = fmaf(-2.f, hi, ss) + 1.f;              // min d2 to vertices

        float t3 = (s1 - 1.f) * (1.f/3.f);                 // simplex projection
        float t2 = (hi + mid - 1.f) * 0.5f;
        float t1 = hi - 1.f;
        float d2_3 = 3.f * t3 * t3;
        float d2_2 = fmaf(lo, lo, 2.f * t2 * t2);
        float d2_1 = fmaf(t1, t1, fmaf(mid, mid, lo * lo));
        float sq = (lo > t3) ? d2_3 : ((mid > t2) ? d2_2 : d2_1);

        sum_in += inside ? d2v : 0.f;
        cnt_in += inside ? 1.f : 0.f;
        mx_out  = inside ? mx_out : fmaxf(mx_out, sq);
    }

    #pragma unroll
    for (int o = 32; o > 0; o >>= 1) {
        sum_in += __shfl_down(sum_in, o);
        cnt_in += __shfl_down(cnt_in, o);
        mx_out  = fmaxf(mx_out, __shfl_down(mx_out, o));
    }
    const int wave = lt >> 6;
    if ((lt & 63) == 0) { s_s[wave] = sum_in; s_c[wave] = cnt_in; s_m[wave] = mx_out; }
    __syncthreads();

    unsigned* wsu = (unsigned*)ws;
    const int g = blockIdx.x & (GROUPS - 1);

    if (lt == 0) {
        float S = 0.f, C = 0.f, M = 0.f;
        #pragma unroll
        for (int i = 0; i < BLOCK/64; ++i) { S += s_s[i]; C += s_c[i]; M = fmaxf(M, s_m[i]); }
        __hip_atomic_store(&ws[blockIdx.x],        S, __ATOMIC_RELAXED, __HIP_MEMORY_SCOPE_AGENT);
        __hip_atomic_store(&ws[NBLK + blockIdx.x], C, __ATOMIC_RELAXED, __HIP_MEMORY_SCOPE_AGENT);
        __hip_atomic_store(&ws[2*NBLK + blockIdx.x], M, __ATOMIC_RELAXED, __HIP_MEMORY_SCOPE_AGENT);
        unsigned ret = __hip_atomic_fetch_add(&wsu[3*NBLK + (g << 4)], 1u,
                                              __ATOMIC_ACQ_REL, __HIP_MEMORY_SCOPE_AGENT);
        s_last = ((ret & (GSIZE - 1)) == (GSIZE - 1)) ? 1 : 0;   // poison-safe
    }
    __syncthreads();

    if (s_last && lt < 64) {
        const int lane = lt;
        // level-1 winner: reduce this group's 32 block-partials
        float S = 0.f, C = 0.f, M = 0.f;
        if (lane < GSIZE) {
            int b = g + (lane << 5);   // blocks with bid % 32 == g
            S = __hip_atomic_load(&ws[b],          __ATOMIC_RELAXED, __HIP_MEMORY_SCOPE_AGENT);
            C = __hip_atomic_load(&ws[NBLK + b],   __ATOMIC_RELAXED, __HIP_MEMORY_SCOPE_AGENT);
            M = __hip_atomic_load(&ws[2*NBLK + b], __ATOMIC_RELAXED, __HIP_MEMORY_SCOPE_AGENT);
        }
        #pragma unroll
        for (int o = 32; o > 0; o >>= 1) {
            S += __shfl_down(S, o);
            C += __shfl_down(C, o);
            M  = fmaxf(M, __shfl_down(M, o));
        }
        int last2 = 0;
        if (lane == 0) {
            __hip_atomic_store(&ws[3584 + g], S, __ATOMIC_RELAXED, __HIP_MEMORY_SCOPE_AGENT);
            __hip_atomic_store(&ws[3616 + g], C, __ATOMIC_RELAXED, __HIP_MEMORY_SCOPE_AGENT);
            __hip_atomic_store(&ws[3648 + g], M, __ATOMIC_RELAXED, __HIP_MEMORY_SCOPE_AGENT);
            unsigned r2 = __hip_atomic_fetch_add(&wsu[3712], 1u,
                                                 __ATOMIC_ACQ_REL, __HIP_MEMORY_SCOPE_AGENT);
            last2 = ((r2 & (GROUPS - 1)) == (GROUPS - 1)) ? 1 : 0;
        }
        last2 = __shfl(last2, 0);
        if (last2) {
            // level-2 winner: reduce the 32 group aggregates
            float S2 = 0.f, C2 = 0.f, M2 = 0.f;
            if (lane < GROUPS) {
                S2 = __hip_atomic_load(&ws[3584 + lane], __ATOMIC_RELAXED, __HIP_MEMORY_SCOPE_AGENT);
                C2 = __hip_atomic_load(&ws[3616 + lane], __ATOMIC_RELAXED, __HIP_MEMORY_SCOPE_AGENT);
                M2 = __hip_atomic_load(&ws[3648 + lane], __ATOMIC_RELAXED, __HIP_MEMORY_SCOPE_AGENT);
            }
            #pragma unroll
            for (int o = 32; o > 0; o >>= 1) {
                S2 += __shfl_down(S2, o);
                C2 += __shfl_down(C2, o);
                M2  = fmaxf(M2, __shfl_down(M2, o));
            }
            if (lane == 0) {
                float li = (C2 > 0.f) ? W_IN * S2 / C2 : 0.f;
                float nout = (float)NP - C2;
                float lo = (nout > 0.f) ? W_OUT * M2 : 0.f;
                out[0] = li + lo;
            }
        }
    }
}

extern "C" void kernel_launch(void* const* d_in, const int* in_sizes, int n_in,
                              void* d_out, int out_size, void* d_ws, size_t ws_size,
                              hipStream_t stream) {
    const float* pts = (const float*)d_in[0];
    float* ws = (float*)d_ws;
    float* out = (float*)d_out;
    pbl_fused<<<NBLK, BLOCK, 0, stream>>>(pts, ws, out);
}

// Round 6
// 10.910 us; speedup vs baseline: 2.6633x; 2.0986x over previous
//
#include <hip/hip_runtime.h>

#define NP 1048576
#define BLOCK 256
#define PPT 4
#define NBLK (NP / (BLOCK * PPT))   /* 1024 */
#define GROUPS 32
#define GSIZE (NBLK / GROUPS)       /* 32 */
#define W_IN 0.001f
#define W_OUT 1.0f
#define TOL 1e-8f
#define SQRT3 1.7320508f

// Drain vector-memory queue: guarantees prior global stores are acked at the
// coherence point before anything issued after this line.
__device__ __forceinline__ void drain_vmem() {
    asm volatile("s_waitcnt vmcnt(0)" ::: "memory");
}

// ws float layout:
//   [0,1024)      per-block S
//   [1024,2048)   per-block C
//   [2048,3072)   per-block M
//   u32 counters level-1 at 3072 + g*16   (64B apart, g<32)
//   group aggregates: S_g at 3584+g, C_g at 3616+g, M_g at 3648+g
//   u32 counter level-2 at 3712
// All cross-block traffic uses RELAXED agent-scope atomics (sc-bit ops that
// hit the coherence point directly) + vmcnt drains for producer ordering.
// No ACQ_REL => no per-block L2 writeback/invalidate maintenance.

__global__ __launch_bounds__(BLOCK) void pbl_fused(
    const float* __restrict__ pts, float* __restrict__ ws, float* __restrict__ out)
{
    __shared__ float s_s[BLOCK/64], s_c[BLOCK/64], s_m[BLOCK/64];
    __shared__ int s_last;

    const int lt = threadIdx.x;
    const int tid = blockIdx.x * BLOCK + lt;
    const float4* p4 = (const float4*)pts;
    float4 f0 = p4[tid*3+0];
    float4 f1 = p4[tid*3+1];
    float4 f2 = p4[tid*3+2];
    float px[PPT] = {f0.x, f0.w, f1.z, f2.y};
    float py[PPT] = {f0.y, f1.x, f1.w, f2.z};
    float pz[PPT] = {f0.z, f1.y, f2.x, f2.w};

    float sum_in = 0.f, cnt_in = 0.f, mx_out = 0.f;
    #pragma unroll
    for (int i = 0; i < PPT; ++i) {
        float ux = fabsf(px[i]), uy = fabsf(py[i]), uz = fabsf(pz[i]);
        float s1 = ux + uy + uz;
        float hi = fmaxf(ux, fmaxf(uy, uz));
        float lo = fminf(ux, fminf(uy, uz));
        float mid = s1 - hi - lo;
        float ss = fmaf(px[i], px[i], fmaf(py[i], py[i], pz[i]*pz[i]));

        bool inside = (s1 - 1.f) <= TOL * SQRT3;           // max plane violation
        float d2v = fmaf(-2.f, hi, ss) + 1.f;              // min d2 to vertices

        float t3 = (s1 - 1.f) * (1.f/3.f);                 // simplex projection
        float t2 = (hi + mid - 1.f) * 0.5f;
        float t1 = hi - 1.f;
        float d2_3 = 3.f * t3 * t3;
        float d2_2 = fmaf(lo, lo, 2.f * t2 * t2);
        float d2_1 = fmaf(t1, t1, fmaf(mid, mid, lo * lo));
        float sq = (lo > t3) ? d2_3 : ((mid > t2) ? d2_2 : d2_1);

        sum_in += inside ? d2v : 0.f;
        cnt_in += inside ? 1.f : 0.f;
        mx_out  = inside ? mx_out : fmaxf(mx_out, sq);
    }

    #pragma unroll
    for (int o = 32; o > 0; o >>= 1) {
        sum_in += __shfl_down(sum_in, o);
        cnt_in += __shfl_down(cnt_in, o);
        mx_out  = fmaxf(mx_out, __shfl_down(mx_out, o));
    }
    const int wave = lt >> 6;
    if ((lt & 63) == 0) { s_s[wave] = sum_in; s_c[wave] = cnt_in; s_m[wave] = mx_out; }
    __syncthreads();

    unsigned* wsu = (unsigned*)ws;
    const int g = blockIdx.x & (GROUPS - 1);

    if (lt == 0) {
        float S = 0.f, C = 0.f, M = 0.f;
        #pragma unroll
        for (int i = 0; i < BLOCK/64; ++i) { S += s_s[i]; C += s_c[i]; M = fmaxf(M, s_m[i]); }
        __hip_atomic_store(&ws[blockIdx.x],          S, __ATOMIC_RELAXED, __HIP_MEMORY_SCOPE_AGENT);
        __hip_atomic_store(&ws[NBLK + blockIdx.x],   C, __ATOMIC_RELAXED, __HIP_MEMORY_SCOPE_AGENT);
        __hip_atomic_store(&ws[2*NBLK + blockIdx.x], M, __ATOMIC_RELAXED, __HIP_MEMORY_SCOPE_AGENT);
        drain_vmem();   // partials acked at coherence point before the increment
        unsigned ret = __hip_atomic_fetch_add(&wsu[3*NBLK + (g << 4)], 1u,
                                              __ATOMIC_RELAXED, __HIP_MEMORY_SCOPE_AGENT);
        s_last = ((ret & (GSIZE - 1)) == (GSIZE - 1)) ? 1 : 0;   // poison-safe
    }
    __syncthreads();

    if (s_last && lt < 64) {
        const int lane = lt;
        // level-1 winner: reduce this group's 32 block-partials
        float S = 0.f, C = 0.f, M = 0.f;
        if (lane < GSIZE) {
            int b = g + (lane << 5);   // blocks with bid % 32 == g
            S = __hip_atomic_load(&ws[b],          __ATOMIC_RELAXED, __HIP_MEMORY_SCOPE_AGENT);
            C = __hip_atomic_load(&ws[NBLK + b],   __ATOMIC_RELAXED, __HIP_MEMORY_SCOPE_AGENT);
            M = __hip_atomic_load(&ws[2*NBLK + b], __ATOMIC_RELAXED, __HIP_MEMORY_SCOPE_AGENT);
        }
        #pragma unroll
        for (int o = 32; o > 0; o >>= 1) {
            S += __shfl_down(S, o);
            C += __shfl_down(C, o);
            M  = fmaxf(M, __shfl_down(M, o));
        }
        int last2 = 0;
        if (lane == 0) {
            __hip_atomic_store(&ws[3584 + g], S, __ATOMIC_RELAXED, __HIP_MEMORY_SCOPE_AGENT);
            __hip_atomic_store(&ws[3616 + g], C, __ATOMIC_RELAXED, __HIP_MEMORY_SCOPE_AGENT);
            __hip_atomic_store(&ws[3648 + g], M, __ATOMIC_RELAXED, __HIP_MEMORY_SCOPE_AGENT);
            drain_vmem();   // aggregates acked before level-2 increment
            unsigned r2 = __hip_atomic_fetch_add(&wsu[3712], 1u,
                                                 __ATOMIC_RELAXED, __HIP_MEMORY_SCOPE_AGENT);
            last2 = ((r2 & (GROUPS - 1)) == (GROUPS - 1)) ? 1 : 0;
        }
        last2 = __shfl(last2, 0);
        if (last2) {
            // level-2 winner: reduce the 32 group aggregates
            float S2 = 0.f, C2 = 0.f, M2 = 0.f;
            if (lane < GROUPS) {
                S2 = __hip_atomic_load(&ws[3584 + lane], __ATOMIC_RELAXED, __HIP_MEMORY_SCOPE_AGENT);
                C2 = __hip_atomic_load(&ws[3616 + lane], __ATOMIC_RELAXED, __HIP_MEMORY_SCOPE_AGENT);
                M2 = __hip_atomic_load(&ws[3648 + lane], __ATOMIC_RELAXED, __HIP_MEMORY_SCOPE_AGENT);
            }
            #pragma unroll
            for (int o = 32; o > 0; o >>= 1) {
                S2 += __shfl_down(S2, o);
                C2 += __shfl_down(C2, o);
                M2  = fmaxf(M2, __shfl_down(M2, o));
            }
            if (lane == 0) {
                float li = (C2 > 0.f) ? W_IN * S2 / C2 : 0.f;
                float nout = (float)NP - C2;
                float lo = (nout > 0.f) ? W_OUT * M2 : 0.f;
                out[0] = li + lo;
            }
        }
    }
}

extern "C" void kernel_launch(void* const* d_in, const int* in_sizes, int n_in,
                              void* d_out, int out_size, void* d_ws, size_t ws_size,
                              hipStream_t stream) {
    const float* pts = (const float*)d_in[0];
    float* ws = (float*)d_ws;
    float* out = (float*)d_out;
    pbl_fused<<<NBLK, BLOCK, 0, stream>>>(pts, ws, out);
}